// Round 1
// baseline (221.672 us; speedup 1.0000x reference)
//
#include <hip/hip_runtime.h>

typedef unsigned int u32;
typedef unsigned long long u64;

#define K_TOP 1000
#define NCLS 80
#define EQCAP 4096
#define NMS_CAP 1024

// ---------------- ws layout (bytes) ----------------
// 0      : u32 hist[9][2048]   = 73728   (zeroed each call)
// 73728  : u32 state[3][8]     = 96      (zeroed each call)
//          state fields: [0]=b1 [1]=b2 [2]=T [3]=kRem1 [4]=kRem2 [5]=needEq [6]=aboveCnt [7]=eqCnt
// 73824  : u32 cand[3][1000]   = 12000
// 85824  : u32 eq[3][4096]     = 49152
// 134976 : u64 skey[4096]      = 32768
// 167744 : f32 nbox[3000][4]   = 48000
// 215744 : u32 nlab[3000]      = 12000
// 227744 : u32 nval[3000]      = 12000
// total ~240 KB

__device__ __forceinline__ float sigmoidf_(float x) {
  if (x >= 0.f) return 1.f / (1.f + expf(-x));
  float e = expf(x);
  return e / (1.f + e);
}
__device__ __forceinline__ u32 key_of(float x) { return __float_as_uint(sigmoidf_(x)); }

// ---------- histogram passes over sigmoid-bit keys ----------
template <int PASS>
__global__ void hist_pass(const float* __restrict__ c0, const float* __restrict__ c1,
                          const float* __restrict__ c2, u32 n0, u32 n1, u32 n2,
                          u32* __restrict__ ws_hist, const u32* __restrict__ ws_state) {
  const int L = blockIdx.y;
  const float* p = (L == 0) ? c0 : ((L == 1) ? c1 : c2);
  const u32 n = (L == 0) ? n0 : ((L == 1) ? n1 : n2);
  u32* hist = ws_hist + (PASS * 3 + L) * 2048;
  const u32* st = ws_state + L * 8;
  __shared__ u32 h[2048];
  for (int i = threadIdx.x; i < 2048; i += blockDim.x) h[i] = 0;
  __syncthreads();
  u32 b1 = 0, pre22 = 0;
  if (PASS == 1) b1 = st[0];
  if (PASS == 2) pre22 = (st[0] << 11) | st[1];
  const u32 n4 = n >> 2;
  const float4* p4 = (const float4*)p;
  for (u32 i = blockIdx.x * blockDim.x + threadIdx.x; i < n4; i += gridDim.x * blockDim.x) {
    float4 v = p4[i];
    float xs[4] = {v.x, v.y, v.z, v.w};
#pragma unroll
    for (int c = 0; c < 4; c++) {
      u32 k = key_of(xs[c]);
      if (PASS == 0) atomicAdd(&h[k >> 21], 1u);
      else if (PASS == 1) { if ((k >> 21) == b1) atomicAdd(&h[(k >> 10) & 2047u], 1u); }
      else { if ((k >> 10) == pre22) atomicAdd(&h[k & 1023u], 1u); }
    }
  }
  // tail (n not multiple of 4 — not expected here, but safe)
  for (u32 i = (n4 << 2) + blockIdx.x * blockDim.x + threadIdx.x; i < n;
       i += gridDim.x * blockDim.x) {
    u32 k = key_of(p[i]);
    if (PASS == 0) atomicAdd(&h[k >> 21], 1u);
    else if (PASS == 1) { if ((k >> 21) == b1) atomicAdd(&h[(k >> 10) & 2047u], 1u); }
    else { if ((k >> 10) == pre22) atomicAdd(&h[k & 1023u], 1u); }
  }
  __syncthreads();
  for (int i = threadIdx.x; i < 2048; i += blockDim.x) {
    u32 v = h[i];
    if (v) atomicAdd(&hist[i], v);
  }
}

// ---------- find boundary bin via parallel suffix scan ----------
template <int PASS>
__global__ __launch_bounds__(1024) void find_pass(const u32* __restrict__ ws_hist,
                                                  u32* __restrict__ ws_state) {
  const int L = blockIdx.x;
  const u32* hist = ws_hist + (PASS * 3 + L) * 2048;
  u32* st = ws_state + L * 8;
  const int NB = (PASS == 2) ? 1024 : 2048;
  __shared__ u32 orig[2048], A[2048], B[2048];
  const int t = threadIdx.x;
  for (int i = t; i < 2048; i += 1024) {
    u32 v = (i < NB) ? hist[i] : 0u;
    orig[i] = v;
    A[i] = v;
  }
  __syncthreads();
  u32 *src = A, *dst = B;
  for (int d = 1; d < 2048; d <<= 1) {
    for (int i = t; i < 2048; i += 1024)
      dst[i] = src[i] + ((i + d < 2048) ? src[i + d] : 0u);
    __syncthreads();
    u32* tmp = src; src = dst; dst = tmp;
  }
  const u32 K_rem = (PASS == 0) ? (u32)K_TOP : ((PASS == 1) ? st[3] : st[4]);
  for (int i = t; i < 2048; i += 1024) {
    if (i < NB) {
      u32 S = src[i];          // inclusive suffix sum: count of keys with bin >= i
      u32 excl = S - orig[i];  // count with bin > i
      if (S >= K_rem && excl < K_rem) {
        u32 kNext = K_rem - excl;
        if (PASS == 0) { st[0] = (u32)i; st[3] = kNext; }
        else if (PASS == 1) { st[1] = (u32)i; st[4] = kNext; }
        else { st[2] = (st[0] << 21) | (st[1] << 10) | (u32)i; st[5] = kNext; }
      }
    }
  }
}

// ---------- compaction: key > T  and  key == T lists ----------
__global__ void compact_k(const float* __restrict__ c0, const float* __restrict__ c1,
                          const float* __restrict__ c2, u32 n0, u32 n1, u32 n2,
                          u32* __restrict__ ws_state, u32* __restrict__ cand,
                          u32* __restrict__ eq) {
  const int L = blockIdx.y;
  const float* p = (L == 0) ? c0 : ((L == 1) ? c1 : c2);
  const u32 n = (L == 0) ? n0 : ((L == 1) ? n1 : n2);
  u32* st = ws_state + L * 8;
  const u32 T = st[2];
  u32* candL = cand + L * K_TOP;
  u32* eqL = eq + L * EQCAP;
  for (u32 i = blockIdx.x * blockDim.x + threadIdx.x; i < n; i += gridDim.x * blockDim.x) {
    u32 k = key_of(p[i]);
    if (k > T) {
      u32 pos = atomicAdd(&st[6], 1u);
      candL[pos] = i;              // count of >T is exactly K_TOP - needEq <= 1000
    } else if (k == T) {
      u32 pos = atomicAdd(&st[7], 1u);
      if (pos < EQCAP) eqL[pos] = i;
    }
  }
}

// ---------- pick smallest-index elements among key == T ----------
__global__ void eqpick_k(u32* __restrict__ ws_state, u32* __restrict__ cand,
                         const u32* __restrict__ eq) {
  const int L = blockIdx.x;
  u32* st = ws_state + L * 8;
  const u32 needEq = st[5];
  u32 n = st[7];
  if (n > EQCAP) n = EQCAP;
  const u32* eqL = eq + L * EQCAP;
  u32* candL = cand + L * K_TOP;
  const u32 basePos = K_TOP - needEq;
  for (u32 i = threadIdx.x; i < n; i += blockDim.x) {
    u32 v = eqL[i];
    u32 rnk = 0;
    for (u32 j = 0; j < n; j++) rnk += (eqL[j] < v) ? 1u : 0u;
    if (rnk < needEq) candL[basePos + rnk] = v;
  }
}

// ---------- build composite sort keys ----------
__global__ void keybuild_k(const float* __restrict__ c0, const float* __restrict__ c1,
                           const float* __restrict__ c2, const u32* __restrict__ cand,
                           u64* __restrict__ skey) {
  int s = blockIdx.x * blockDim.x + threadIdx.x;
  if (s >= 4096) return;
  if (s >= 3 * K_TOP) { skey[s] = 0ull; return; }
  int L = s / K_TOP;
  u32 e = cand[L * K_TOP + (s - L * K_TOP)];
  const float* p = (L == 0) ? c0 : ((L == 1) ? c1 : c2);
  float sc = sigmoidf_(p[e]);
  u32 hi = (sc > 0.05f) ? __float_as_uint(sc) : 0u;  // invalid -> -inf equivalent
  u32 v = ((u32)L << 23) | e;                        // concat-position tie-break
  skey[s] = ((u64)hi << 32) | (u64)(u32)(~v);
}

// ---------- single-block bitonic sort, descending, 4096 keys ----------
__global__ __launch_bounds__(1024) void sort_k(u64* __restrict__ skey) {
  __shared__ u64 sh[4096];
  const int t = threadIdx.x;
  for (int i = t; i < 4096; i += 1024) sh[i] = skey[i];
  __syncthreads();
  for (int k = 2; k <= 4096; k <<= 1) {
    for (int j = k >> 1; j > 0; j >>= 1) {
      for (int i = t; i < 4096; i += 1024) {
        int ixj = i ^ j;
        if (ixj > i) {
          u64 a = sh[i], b = sh[ixj];
          bool descSeg = ((i & k) == 0);
          bool doSwap = descSeg ? (a < b) : (a > b);
          if (doSwap) { sh[i] = b; sh[ixj] = a; }
        }
      }
      __syncthreads();
    }
  }
  for (int i = t; i < 4096; i += 1024) skey[i] = sh[i];
}

// ---------- decode sorted candidates: DFL box + outputs ----------
__global__ void decode_k(const float* __restrict__ c0, const float* __restrict__ c1,
                         const float* __restrict__ c2, const float* __restrict__ r0,
                         const float* __restrict__ r1, const float* __restrict__ r2,
                         const u64* __restrict__ skey, float* __restrict__ out,
                         float* __restrict__ nbox, u32* __restrict__ nlab,
                         u32* __restrict__ nval) {
  int r = blockIdx.x * blockDim.x + threadIdx.x;
  if (r >= 3 * K_TOP) return;
  u64 key = skey[r];
  u32 v = (~(u32)key) & 0x01FFFFFFu;
  int L = (int)(v >> 23);
  u32 e = v & 0x7FFFFFu;
  const float* cp = (L == 0) ? c0 : ((L == 1) ? c1 : c2);
  const float* rp = (L == 0) ? r0 : ((L == 1) ? r1 : r2);
  float sc = sigmoidf_(cp[e]);
  u32 anchor = e / NCLS;
  u32 label = e - anchor * NCLS;
  const int stride = 8 << L;
  const u32 fmask = (256u >> L) - 1u;
  float ax = ((float)(anchor & fmask) + 0.5f) * (float)stride;
  float ay = ((float)(anchor >> (8 - L)) + 0.5f) * (float)stride;
  const float* rg = rp + (u64)anchor * 68u;
  float d[4];
#pragma unroll
  for (int s4 = 0; s4 < 4; s4++) {
    float m = rg[s4 * 17];
#pragma unroll
    for (int b = 1; b < 17; b++) m = fmaxf(m, rg[s4 * 17 + b]);
    float den = 0.f, num = 0.f;
#pragma unroll
    for (int b = 0; b < 17; b++) {
      float ev = expf(rg[s4 * 17 + b] - m);
      den += ev;
      num += ev * (float)b;
    }
    d[s4] = num / den;
  }
  float x1 = ax - d[0] * (float)stride, y1 = ay - d[1] * (float)stride;
  float x2 = ax + d[2] * (float)stride, y2 = ay + d[3] * (float)stride;
  const float inv = 1.f / 2048.f;
  out[r * 4 + 0] = fminf(fmaxf(x1 * inv, 0.f), 1.f);
  out[r * 4 + 1] = fminf(fmaxf(y1 * inv, 0.f), 1.f);
  out[r * 4 + 2] = fminf(fmaxf(x2 * inv, 0.f), 1.f);
  out[r * 4 + 3] = fminf(fmaxf(y2 * inv, 0.f), 1.f);
  out[12000 + r] = sc;
  out[15000 + r] = (float)label;
  out[18000 + r] = 0.f;  // keep default; NMS sets survivors
  nbox[r * 4 + 0] = x1; nbox[r * 4 + 1] = y1; nbox[r * 4 + 2] = x2; nbox[r * 4 + 3] = y2;
  nlab[r] = label;
  nval[r] = (sc > 0.05f) ? 1u : 0u;
}

// ---------- per-class sequential NMS (cross-class IoU is exactly 0) ----------
__global__ __launch_bounds__(64) void nms_k(const float* __restrict__ nbox,
                                            const u32* __restrict__ nlab,
                                            const u32* __restrict__ nval,
                                            float* __restrict__ keep_out) {
  const u32 c = blockIdx.x;
  const int lane = threadIdx.x;
  __shared__ float bx[NMS_CAP][4];
  __shared__ unsigned short pos[NMS_CAP];
  __shared__ unsigned char flg[NMS_CAP];
  u32 base = 0;
  for (int it = 0; it < (3 * K_TOP + 63) / 64; ++it) {
    int r = it * 64 + lane;
    bool p = (r < 3 * K_TOP) && (nlab[r] == c) && (nval[r] != 0u);
    u64 m = __ballot(p);
    int rnk = __popcll(m & ((1ull << lane) - 1ull));
    if (p && (base + (u32)rnk) < NMS_CAP) {
      u32 q = base + (u32)rnk;
      bx[q][0] = nbox[r * 4 + 0];
      bx[q][1] = nbox[r * 4 + 1];
      bx[q][2] = nbox[r * 4 + 2];
      bx[q][3] = nbox[r * 4 + 3];
      pos[q] = (unsigned short)r;
    }
    base += (u32)__popcll(m);
  }
  u32 mm = base;
  if (mm > NMS_CAP) mm = NMS_CAP;
  for (u32 j = lane; j < mm; j += 64) flg[j] = 1;
  __syncthreads();
  for (u32 i = 0; i < mm; i++) {
    if (flg[i]) {
      float bi0 = bx[i][0], bi1 = bx[i][1], bi2 = bx[i][2], bi3 = bx[i][3];
      float ai = fmaxf(bi2 - bi0, 0.f) * fmaxf(bi3 - bi1, 0.f);
      for (u32 j = i + 1 + (u32)lane; j < mm; j += 64) {
        if (flg[j]) {
          float xx1 = fmaxf(bi0, bx[j][0]), yy1 = fmaxf(bi1, bx[j][1]);
          float xx2 = fminf(bi2, bx[j][2]), yy2 = fminf(bi3, bx[j][3]);
          float w = fmaxf(xx2 - xx1, 0.f), h = fmaxf(yy2 - yy1, 0.f);
          float inter = w * h;
          float aj = fmaxf(bx[j][2] - bx[j][0], 0.f) * fmaxf(bx[j][3] - bx[j][1], 0.f);
          float un = ai + aj - inter;
          float iou = inter / fmaxf(un, 1e-9f);
          if (iou > 0.6f) flg[j] = 0;
        }
      }
    }
    __syncthreads();
  }
  for (u32 j = lane; j < mm; j += 64)
    if (flg[j]) keep_out[pos[j]] = 1.0f;
}

extern "C" void kernel_launch(void* const* d_in, const int* in_sizes, int n_in,
                              void* d_out, int out_size, void* d_ws, size_t ws_size,
                              hipStream_t stream) {
  const float *cls[3], *reg[3];
  u32 n[3];
  if (in_sizes[1] > 2000000) {
    // dict order interleaved: cls0, reg0, cls1, reg1, cls2, reg2
    cls[0] = (const float*)d_in[0]; reg[0] = (const float*)d_in[1];
    cls[1] = (const float*)d_in[2]; reg[1] = (const float*)d_in[3];
    cls[2] = (const float*)d_in[4]; reg[2] = (const float*)d_in[5];
    n[0] = (u32)in_sizes[0]; n[1] = (u32)in_sizes[2]; n[2] = (u32)in_sizes[4];
  } else {
    // grouped: cls0, cls1, cls2, reg0, reg1, reg2
    cls[0] = (const float*)d_in[0]; cls[1] = (const float*)d_in[1]; cls[2] = (const float*)d_in[2];
    reg[0] = (const float*)d_in[3]; reg[1] = (const float*)d_in[4]; reg[2] = (const float*)d_in[5];
    n[0] = (u32)in_sizes[0]; n[1] = (u32)in_sizes[1]; n[2] = (u32)in_sizes[2];
  }
  char* w = (char*)d_ws;
  u32* hist = (u32*)(w);
  u32* state = (u32*)(w + 73728);
  u32* cand = (u32*)(w + 73824);
  u32* eq = (u32*)(w + 85824);
  u64* skey = (u64*)(w + 134976);
  float* nbox = (float*)(w + 167744);
  u32* nlab = (u32*)(w + 215744);
  u32* nval = (u32*)(w + 227744);
  float* out = (float*)d_out;

  hipMemsetAsync(d_ws, 0, 73824, stream);  // hists + state/counters

  dim3 hb(256), hg(1024, 3);
  hist_pass<0><<<hg, hb, 0, stream>>>(cls[0], cls[1], cls[2], n[0], n[1], n[2], hist, state);
  find_pass<0><<<dim3(3), dim3(1024), 0, stream>>>(hist, state);
  hist_pass<1><<<hg, hb, 0, stream>>>(cls[0], cls[1], cls[2], n[0], n[1], n[2], hist, state);
  find_pass<1><<<dim3(3), dim3(1024), 0, stream>>>(hist, state);
  hist_pass<2><<<hg, hb, 0, stream>>>(cls[0], cls[1], cls[2], n[0], n[1], n[2], hist, state);
  find_pass<2><<<dim3(3), dim3(1024), 0, stream>>>(hist, state);
  compact_k<<<dim3(1024, 3), hb, 0, stream>>>(cls[0], cls[1], cls[2], n[0], n[1], n[2], state,
                                              cand, eq);
  eqpick_k<<<dim3(3), dim3(256), 0, stream>>>(state, cand, eq);
  keybuild_k<<<dim3(16), dim3(256), 0, stream>>>(cls[0], cls[1], cls[2], cand, skey);
  sort_k<<<dim3(1), dim3(1024), 0, stream>>>(skey);
  decode_k<<<dim3(12), dim3(256), 0, stream>>>(cls[0], cls[1], cls[2], reg[0], reg[1], reg[2],
                                               skey, out, nbox, nlab, nval);
  nms_k<<<dim3(80), dim3(64), 0, stream>>>(nbox, nlab, nval, out + 18000);
}

// Round 2
// 155.226 us; speedup vs baseline: 1.4281x; 1.4281x over previous
//
#include <hip/hip_runtime.h>

typedef unsigned int u32;
typedef unsigned long long u64;
typedef unsigned char u8;

#define K_TOP 1000
#define NCLS 80
#define CAND_CAP 4096
#define NMS_CAP 1024
#define GCH 750  // chunk size for global rank (4 chunks of 750 = 3000)

// ---------------- ws layout (bytes) ----------------
// 0      : u32 hist[3][2048]  = 24576  (zeroed)
// 24576  : u32 state[3][8]    = 96     (zeroed)  [0]=b1 [1]=candCount
// 24672  : u32 ranks3k[3000]  = 12000  (zeroed)
// 36672  : u64 cand[3][4096]  = 98304
// 134976 : u64 sel_out[3000]  = 24000  (key32<<32 | ~elem_idx, indexed by L*1000+rank)
// 158976 : u64 skey[3000]     = 24000  (global sort keys)
// 182976 : f32 nbox[3000][4]  = 48000
// 230976 : u8  nlab[3000]     = 3000
// 233976 : u8  nval[3000]     = 3000
// total 236976 B

// order-preserving transform of float bits (monotonic with float value)
__device__ __forceinline__ u32 okey(float x) {
  u32 b = __float_as_uint(x);
  return (b & 0x80000000u) ? ~b : (b | 0x80000000u);
}
__device__ __forceinline__ float okey_inv_f(u32 k) {
  u32 b = (k & 0x80000000u) ? (k ^ 0x80000000u) : ~k;
  return __uint_as_float(b);
}
__device__ __forceinline__ float sigmoidf_(float x) {
  if (x >= 0.f) return 1.f / (1.f + expf(-x));
  float e = expf(x);
  return e / (1.f + e);
}

// ---------- single histogram pass over top 11 bits of transformed key ----------
__global__ __launch_bounds__(256) void hist0_k(const float* __restrict__ c0,
                                               const float* __restrict__ c1,
                                               const float* __restrict__ c2, u32 n0, u32 n1,
                                               u32 n2, u32* __restrict__ hist) {
  const int L = blockIdx.y;
  const float* p = (L == 0) ? c0 : ((L == 1) ? c1 : c2);
  const u32 n = (L == 0) ? n0 : ((L == 1) ? n1 : n2);
  u32* h = hist + L * 2048;
  __shared__ u32 sh[2048][4];  // 4 replicas to cut same-address atomic serialization
  for (int i = threadIdx.x; i < 2048 * 4; i += 256) ((u32*)sh)[i] = 0;
  __syncthreads();
  const int rep = threadIdx.x & 3;
  const u32 n4 = n >> 2;
  const float4* p4 = (const float4*)p;
  for (u32 i = blockIdx.x * blockDim.x + threadIdx.x; i < n4; i += gridDim.x * blockDim.x) {
    float4 v = p4[i];
    atomicAdd(&sh[okey(v.x) >> 21][rep], 1u);
    atomicAdd(&sh[okey(v.y) >> 21][rep], 1u);
    atomicAdd(&sh[okey(v.z) >> 21][rep], 1u);
    atomicAdd(&sh[okey(v.w) >> 21][rep], 1u);
  }
  for (u32 i = (n4 << 2) + blockIdx.x * blockDim.x + threadIdx.x; i < n;
       i += gridDim.x * blockDim.x)
    atomicAdd(&sh[okey(p[i]) >> 21][rep], 1u);
  __syncthreads();
  for (int i = threadIdx.x; i < 2048; i += 256) {
    u32 v = sh[i][0] + sh[i][1] + sh[i][2] + sh[i][3];
    if (v) atomicAdd(&h[i], v);
  }
}

// ---------- find boundary bin b1: largest b with suffix_count(b) >= K_TOP ----------
__global__ __launch_bounds__(1024) void find0_k(const u32* __restrict__ hist,
                                                u32* __restrict__ state) {
  const int L = blockIdx.x;
  const u32* h = hist + L * 2048;
  u32* st = state + L * 8;
  __shared__ u32 orig[2048], A[2048], B[2048];
  const int t = threadIdx.x;
  for (int i = t; i < 2048; i += 1024) {
    u32 v = h[i];
    orig[i] = v;
    A[i] = v;
  }
  __syncthreads();
  u32 *src = A, *dst = B;
  for (int d = 1; d < 2048; d <<= 1) {
    for (int i = t; i < 2048; i += 1024)
      dst[i] = src[i] + ((i + d < 2048) ? src[i + d] : 0u);
    __syncthreads();
    u32* tmp = src; src = dst; dst = tmp;
  }
  for (int i = t; i < 2048; i += 1024) {
    u32 S = src[i];           // count of keys with bin >= i
    u32 excl = S - orig[i];   // count with bin > i
    if (S >= (u32)K_TOP && excl < (u32)K_TOP) st[0] = (u32)i;
  }
}

// ---------- compact: all elements with top-11-bit prefix >= b1 ----------
__global__ __launch_bounds__(256) void compact1_k(const float* __restrict__ c0,
                                                  const float* __restrict__ c1,
                                                  const float* __restrict__ c2, u32 n0, u32 n1,
                                                  u32 n2, u32* __restrict__ state,
                                                  u64* __restrict__ cand) {
  const int L = blockIdx.y;
  const float* p = (L == 0) ? c0 : ((L == 1) ? c1 : c2);
  const u32 n = (L == 0) ? n0 : ((L == 1) ? n1 : n2);
  u32* st = state + L * 8;
  const u32 b1 = st[0];
  u64* cl = cand + (u64)L * CAND_CAP;
  const u32 n4 = n >> 2;
  const float4* p4 = (const float4*)p;
  for (u32 i = blockIdx.x * blockDim.x + threadIdx.x; i < n4; i += gridDim.x * blockDim.x) {
    float4 v = p4[i];
    float xs[4] = {v.x, v.y, v.z, v.w};
#pragma unroll
    for (int c = 0; c < 4; c++) {
      u32 k = okey(xs[c]);
      if ((k >> 21) >= b1) {
        u32 pos = atomicAdd(&st[1], 1u);
        if (pos < CAND_CAP) cl[pos] = ((u64)k << 32) | (u64)(u32)(~(i * 4u + (u32)c));
      }
    }
  }
  for (u32 i = (n4 << 2) + blockIdx.x * blockDim.x + threadIdx.x; i < n;
       i += gridDim.x * blockDim.x) {
    u32 k = okey(p[i]);
    if ((k >> 21) >= b1) {
      u32 pos = atomicAdd(&st[1], 1u);
      if (pos < CAND_CAP) cl[pos] = ((u64)k << 32) | (u64)(u32)(~i);
    }
  }
}

// ---------- exact rank-select of top-1000 per level + global key build ----------
// rank among candidates by K desc (K unique: low bits = ~idx). rank < 1000 -> selected;
// within-level topk rank = rank  (matches stable top_k: score desc, idx asc).
__global__ __launch_bounds__(256) void sel_k(const u32* __restrict__ state,
                                             const u64* __restrict__ cand,
                                             u64* __restrict__ sel_out, u64* __restrict__ skey) {
  const int L = blockIdx.y;
  u32 cnt = state[L * 8 + 1];
  if (cnt > CAND_CAP) cnt = CAND_CAP;
  const u32 base = blockIdx.x * 256u;
  if (base >= cnt) return;
  __shared__ u64 sh[CAND_CAP];  // 32 KB
  const u64* cl = cand + (u64)L * CAND_CAP;
  for (u32 i = threadIdx.x; i < cnt; i += 256) sh[i] = cl[i];
  __syncthreads();
  const u32 i = base + threadIdx.x;
  if (i >= cnt) return;
  const u64 K = sh[i];
  u32 rank = 0;
  for (u32 j = 0; j < cnt; j++) rank += (sh[j] > K) ? 1u : 0u;
  if (rank < (u32)K_TOP) {
    const u32 pos = (u32)L * K_TOP + rank;
    sel_out[pos] = K;
    const u32 k32 = (u32)(K >> 32);
    const float sc = sigmoidf_(okey_inv_f(k32));
    // global stable-argsort key: score desc (invalid -> -inf class), tie -> concat pos asc
    const u32 hi = (sc > 0.05f) ? __float_as_uint(sc) : 0u;
    skey[pos] = ((u64)hi << 32) | (u64)(u32)(~pos);
  }
}

// ---------- global rank of the 3000 keys (chunked partial counts) ----------
__global__ __launch_bounds__(256) void rank_k(const u64* __restrict__ skey,
                                              u32* __restrict__ ranks) {
  const u32 jb = blockIdx.y * GCH;
  __shared__ u64 sh[GCH];
  for (u32 i = threadIdx.x; i < GCH; i += 256) sh[i] = skey[jb + i];
  __syncthreads();
  const u32 r = blockIdx.x * 256u + threadIdx.x;
  if (r >= 3 * K_TOP) return;
  const u64 K = skey[r];
  u32 c = 0;
  for (u32 j = 0; j < GCH; j++) c += (sh[j] > K) ? 1u : 0u;
  if (c) atomicAdd(&ranks[r], c);
}

// ---------- decode + scatter to sorted position ----------
__global__ __launch_bounds__(256) void decode_k(const float* __restrict__ r0,
                                                const float* __restrict__ r1,
                                                const float* __restrict__ r2,
                                                const u64* __restrict__ sel_out,
                                                const u32* __restrict__ ranks,
                                                float* __restrict__ out, float* __restrict__ nbox,
                                                u8* __restrict__ nlab, u8* __restrict__ nval) {
  const u32 r = blockIdx.x * 256u + threadIdx.x;
  if (r >= 3 * K_TOP) return;
  const u32 p = ranks[r];           // final sorted position
  const u64 K = sel_out[r];
  const int L = (int)(r / K_TOP);
  const u32 e = ~(u32)K;            // flat element index within level
  const float* rp = (L == 0) ? r0 : ((L == 1) ? r1 : r2);
  const float sc = sigmoidf_(okey_inv_f((u32)(K >> 32)));
  const u32 anchor = e / NCLS;
  const u32 label = e - anchor * NCLS;
  const int stride = 8 << L;
  const u32 fmask = (256u >> L) - 1u;
  const float ax = ((float)(anchor & fmask) + 0.5f) * (float)stride;
  const float ay = ((float)(anchor >> (8 - L)) + 0.5f) * (float)stride;
  const float* rg = rp + (u64)anchor * 68u;
  float d[4];
#pragma unroll
  for (int s4 = 0; s4 < 4; s4++) {
    float m = rg[s4 * 17];
#pragma unroll
    for (int b = 1; b < 17; b++) m = fmaxf(m, rg[s4 * 17 + b]);
    float den = 0.f, num = 0.f;
#pragma unroll
    for (int b = 0; b < 17; b++) {
      float ev = expf(rg[s4 * 17 + b] - m);
      den += ev;
      num += ev * (float)b;
    }
    d[s4] = num / den;
  }
  const float x1 = ax - d[0] * (float)stride, y1 = ay - d[1] * (float)stride;
  const float x2 = ax + d[2] * (float)stride, y2 = ay + d[3] * (float)stride;
  const float inv = 1.f / 2048.f;
  out[p * 4 + 0] = fminf(fmaxf(x1 * inv, 0.f), 1.f);
  out[p * 4 + 1] = fminf(fmaxf(y1 * inv, 0.f), 1.f);
  out[p * 4 + 2] = fminf(fmaxf(x2 * inv, 0.f), 1.f);
  out[p * 4 + 3] = fminf(fmaxf(y2 * inv, 0.f), 1.f);
  out[12000 + p] = sc;
  out[15000 + p] = (float)label;
  out[18000 + p] = 0.f;  // keep default; NMS sets survivors
  nbox[p * 4 + 0] = x1; nbox[p * 4 + 1] = y1; nbox[p * 4 + 2] = x2; nbox[p * 4 + 3] = y2;
  nlab[p] = (u8)label;
  nval[p] = (sc > 0.05f) ? (u8)1 : (u8)0;
}

// ---------- per-class sequential NMS; 1 wave per class, no barriers ----------
__global__ __launch_bounds__(64) void nms_k(const float* __restrict__ nbox,
                                            const u8* __restrict__ nlab,
                                            const u8* __restrict__ nval,
                                            float* __restrict__ keep_out) {
  const u32 c = blockIdx.x;
  const int lane = threadIdx.x;
  __shared__ float bx[NMS_CAP][4];
  __shared__ unsigned short pos[NMS_CAP];
  __shared__ u8 flg[NMS_CAP];
  u32 base = 0;
  for (int it = 0; it < (3 * K_TOP + 63) / 64; ++it) {
    int r = it * 64 + lane;
    bool p = (r < 3 * K_TOP) && (nlab[r] == (u8)c) && (nval[r] != 0);
    u64 m = __ballot(p);
    int rnk = __popcll(m & ((1ull << lane) - 1ull));
    if (p && (base + (u32)rnk) < NMS_CAP) {
      u32 q = base + (u32)rnk;
      bx[q][0] = nbox[r * 4 + 0];
      bx[q][1] = nbox[r * 4 + 1];
      bx[q][2] = nbox[r * 4 + 2];
      bx[q][3] = nbox[r * 4 + 3];
      pos[q] = (unsigned short)r;
    }
    base += (u32)__popcll(m);
  }
  u32 mm = base;
  if (mm > NMS_CAP) mm = NMS_CAP;
  for (u32 j = lane; j < mm; j += 64) flg[j] = 1;
  // single wave: LDS ops are program-ordered, no __syncthreads needed
  for (u32 i = 0; i < mm; i++) {
    if (flg[i]) {
      float bi0 = bx[i][0], bi1 = bx[i][1], bi2 = bx[i][2], bi3 = bx[i][3];
      float ai = fmaxf(bi2 - bi0, 0.f) * fmaxf(bi3 - bi1, 0.f);
      for (u32 j = i + 1 + (u32)lane; j < mm; j += 64) {
        if (flg[j]) {
          float xx1 = fmaxf(bi0, bx[j][0]), yy1 = fmaxf(bi1, bx[j][1]);
          float xx2 = fminf(bi2, bx[j][2]), yy2 = fminf(bi3, bx[j][3]);
          float w = fmaxf(xx2 - xx1, 0.f), h = fmaxf(yy2 - yy1, 0.f);
          float inter = w * h;
          float aj = fmaxf(bx[j][2] - bx[j][0], 0.f) * fmaxf(bx[j][3] - bx[j][1], 0.f);
          float un = ai + aj - inter;
          float iou = inter / fmaxf(un, 1e-9f);
          if (iou > 0.6f) flg[j] = 0;
        }
      }
    }
  }
  for (u32 j = lane; j < mm; j += 64)
    if (flg[j]) keep_out[pos[j]] = 1.0f;
}

extern "C" void kernel_launch(void* const* d_in, const int* in_sizes, int n_in,
                              void* d_out, int out_size, void* d_ws, size_t ws_size,
                              hipStream_t stream) {
  const float *cls[3], *reg[3];
  u32 n[3];
  if (in_sizes[1] > 2000000) {
    // interleaved: cls0, reg0, cls1, reg1, cls2, reg2
    cls[0] = (const float*)d_in[0]; reg[0] = (const float*)d_in[1];
    cls[1] = (const float*)d_in[2]; reg[1] = (const float*)d_in[3];
    cls[2] = (const float*)d_in[4]; reg[2] = (const float*)d_in[5];
    n[0] = (u32)in_sizes[0]; n[1] = (u32)in_sizes[2]; n[2] = (u32)in_sizes[4];
  } else {
    // grouped: cls0, cls1, cls2, reg0, reg1, reg2
    cls[0] = (const float*)d_in[0]; cls[1] = (const float*)d_in[1]; cls[2] = (const float*)d_in[2];
    reg[0] = (const float*)d_in[3]; reg[1] = (const float*)d_in[4]; reg[2] = (const float*)d_in[5];
    n[0] = (u32)in_sizes[0]; n[1] = (u32)in_sizes[1]; n[2] = (u32)in_sizes[2];
  }
  char* w = (char*)d_ws;
  u32* hist = (u32*)(w);                 // 24576
  u32* state = (u32*)(w + 24576);        // 96
  u32* ranks = (u32*)(w + 24672);        // 12000
  u64* cand = (u64*)(w + 36672);         // 98304
  u64* sel_out = (u64*)(w + 134976);     // 24000
  u64* skey = (u64*)(w + 158976);        // 24000
  float* nbox = (float*)(w + 182976);    // 48000
  u8* nlab = (u8*)(w + 230976);          // 3000
  u8* nval = (u8*)(w + 233976);          // 3000
  float* out = (float*)d_out;

  hipMemsetAsync(d_ws, 0, 36672, stream);  // hist + state + ranks

  hist0_k<<<dim3(256, 3), dim3(256), 0, stream>>>(cls[0], cls[1], cls[2], n[0], n[1], n[2], hist);
  find0_k<<<dim3(3), dim3(1024), 0, stream>>>(hist, state);
  compact1_k<<<dim3(256, 3), dim3(256), 0, stream>>>(cls[0], cls[1], cls[2], n[0], n[1], n[2],
                                                     state, cand);
  sel_k<<<dim3(16, 3), dim3(256), 0, stream>>>(state, cand, sel_out, skey);
  rank_k<<<dim3(12, 4), dim3(256), 0, stream>>>(skey, ranks);
  decode_k<<<dim3(12), dim3(256), 0, stream>>>(reg[0], reg[1], reg[2], sel_out, ranks, out, nbox,
                                               nlab, nval);
  nms_k<<<dim3(80), dim3(64), 0, stream>>>(nbox, nlab, nval, out + 18000);
}